// Round 8
// baseline (238.126 us; speedup 1.0000x reference)
//
#include <hip/hip_runtime.h>
#include <hip/hip_bf16.h>
#include <cstdint>

#define BATCH 4
#define S_LEN 2048
#define D_DIM 1024

typedef __attribute__((ext_vector_type(4))) float f32x4_t;
typedef __attribute__((ext_vector_type(8))) __bf16 bf16x8_t;

__device__ __forceinline__ ushort f32_to_bf16(float f) {
    uint32_t u = __float_as_uint(f);
    uint32_t r = (u + 0x7FFFu + ((u >> 16) & 1u)) >> 16;
    return (ushort)r;
}

// ---------------- fp32 -> bf16 convert, 3 tensors in one launch ----------------
__global__ __launch_bounds__(256)
void cvt3_kernel(const float* __restrict__ a, const float* __restrict__ b,
                 const float* __restrict__ c, ushort* __restrict__ out, int n4) {
    int z = blockIdx.y;
    const float* src = (z == 0) ? a : ((z == 1) ? b : c);
    ushort* dst = out + (size_t)z * n4 * 4;
    int idx = blockIdx.x * blockDim.x + threadIdx.x;
    int stride = gridDim.x * blockDim.x;
    const float4* in4 = (const float4*)src;
    ushort4* out4 = (ushort4*)dst;
    for (int i = idx; i < n4; i += stride) {
        float4 v = in4[i];
        ushort4 o;
        o.x = f32_to_bf16(v.x);
        o.y = f32_to_bf16(v.y);
        o.z = f32_to_bf16(v.z);
        o.w = f32_to_bf16(v.w);
        out4[i] = o;
    }
}

// ---------------- fp32 -> bf16 convert, 2 tensors (Wk, Wq) ----------------
__global__ __launch_bounds__(256)
void cvt2_kernel(const float* __restrict__ a, const float* __restrict__ b,
                 ushort* __restrict__ out, int n4) {
    int z = blockIdx.y;
    const float* src = (z == 0) ? a : b;
    ushort* dst = out + (size_t)z * n4 * 4;
    int idx = blockIdx.x * blockDim.x + threadIdx.x;
    int stride = gridDim.x * blockDim.x;
    const float4* in4 = (const float4*)src;
    ushort4* out4 = (ushort4*)dst;
    for (int i = idx; i < n4; i += stride) {
        float4 v = in4[i];
        ushort4 o;
        o.x = f32_to_bf16(v.x);
        o.y = f32_to_bf16(v.y);
        o.z = f32_to_bf16(v.z);
        o.w = f32_to_bf16(v.w);
        out4[i] = o;
    }
}

// ---------------- fp32 [rows][cols] -> bf16 [cols][rows] (Wv) ----------------
__global__ __launch_bounds__(256)
void transpose_cvt_kernel(const float* __restrict__ in, ushort* __restrict__ out,
                          int rows, int cols) {
    __shared__ ushort tile[64][66];
    int r0 = blockIdx.y * 64, c0 = blockIdx.x * 64;
    int t = threadIdx.x;
    int cr = t & 63;
    int cc = t >> 6;
    #pragma unroll
    for (int i = 0; i < 16; ++i) {
        int r = cc * 16 + i;
        tile[r][cr] = f32_to_bf16(in[(size_t)(r0 + r) * cols + (c0 + cr)]);
    }
    __syncthreads();
    #pragma unroll
    for (int i = 0; i < 16; ++i) {
        int c = cc * 16 + i;
        out[(size_t)(c0 + c) * rows + (r0 + cr)] = tile[cr][c];
    }
}

// ---------------- bias2 = [0 | bv], zb = 0 ----------------
__global__ __launch_bounds__(256)
void fill_kernel(const float* __restrict__ bv, float* __restrict__ bias2,
                 float* __restrict__ zb) {
    int i = blockIdx.x * blockDim.x + threadIdx.x;   // 0..2047
    bias2[i] = (i < D_DIM) ? 0.f : bv[i - D_DIM];
    zb[i] = 0.f;
}

// ---------------- hv[e] = Wk[e,:] . bq ----------------
__global__ __launch_bounds__(256)
void hv_kernel(const float* __restrict__ Wk, const float* __restrict__ bq,
               float* __restrict__ hv) {
    int wave = threadIdx.x >> 6, lane = threadIdx.x & 63;
    int r = blockIdx.x * 4 + wave;     // 1024 rows, grid 256
    const float* row = Wk + (size_t)r * D_DIM;
    float s = 0.f;
    #pragma unroll
    for (int it = 0; it < 16; ++it)
        s += row[it * 64 + lane] * bq[it * 64 + lane];
    #pragma unroll
    for (int off = 32; off > 0; off >>= 1)
        s += __shfl_xor(s, off);
    if (lane == 0) hv[r] = s;
}

// ---------------- w[r] = (xk[r,:] . hv) / 32 ----------------
__global__ __launch_bounds__(256)
void wvec_kernel(const ushort* __restrict__ xk, const float* __restrict__ hv,
                 float* __restrict__ w) {
    int wave = threadIdx.x >> 6, lane = threadIdx.x & 63;
    int r = blockIdx.x * 4 + wave;     // 8192 rows, grid 2048
    const ushort* row = xk + (size_t)r * D_DIM + lane * 16;
    const float* hp = hv + lane * 16;
    float s = 0.f;
    #pragma unroll
    for (int it = 0; it < 16; ++it) {
        uint32_t u = row[it];
        s += __uint_as_float(u << 16) * hp[it];
    }
    #pragma unroll
    for (int off = 32; off > 0; off >>= 1)
        s += __shfl_xor(s, off);
    if (lane == 0) w[r] = s * 0.03125f;
}

// =====================================================================
// Occupancy-2 GEMM: 128x256 tile, BK=32, 8 waves (2x4, wave 64x64),
// 3 LDS slots (72 KB -> 2 blocks/CU), 2-ahead staging, vmcnt(3) steady.
// C = A(MxK) * Bt(NxK)^T.
// =====================================================================
enum { MODE_PROJ = 0, MODE_MT = 1, MODE_LOGITS = 2, MODE_OUT = 3 };

#define GATE(N) do { asm volatile("s_waitcnt vmcnt(" #N ")" ::: "memory"); \
    __builtin_amdgcn_sched_barrier(0); } while (0)
#define GLOAD(dst, src) __builtin_amdgcn_global_load_lds( \
    (const __attribute__((address_space(1))) uint32_t*)(src), \
    (__attribute__((address_space(3))) uint32_t*)(dst), 16, 0, 0)

// bijective XCD swizzle over (x,y) grid (requires nwg%8==0)
__device__ __forceinline__ void xcd_swizzle(int& bc, int& br) {
    int gx = gridDim.x;
    int nwg = gx * gridDim.y;
    int orig = blockIdx.y * gx + blockIdx.x;
    int xcd = orig & 7, idx = orig >> 3;
    int wgid = xcd * (nwg >> 3) + idx;
    bc = wgid % gx;
    br = wgid / gx;
}

template<int MODE>
__global__ __launch_bounds__(512, 4)
void gemm_t_kernel(const ushort* __restrict__ A, const ushort* __restrict__ Bt,
                   const float* __restrict__ bias, void* __restrict__ Cout,
                   ushort* __restrict__ vpTp,
                   int nkt0, int lda, int ldb, int ldc,
                   long strideA, long strideB, long strideC, float scale) {
    __shared__ ushort As[3][128 * 32];   // 3 x 8 KB
    __shared__ ushort Bs[3][256 * 32];   // 3 x 16 KB
    int bc, br;
    xcd_swizzle(bc, br);
    int bz = blockIdx.z;
    if (MODE == MODE_LOGITS && 2 * bc > br) return;   // fully-masked causal block
    const ushort* Ab = (MODE == MODE_PROJ) ? A + (size_t)((bc >> 2) * 2) * strideA
                                           : A + (size_t)bz * strideA;
    const ushort* Bb = Bt + (size_t)bz * strideB;
    int brow = br * 128, bcol = bc * 256;
    int t = threadIdx.x, lane = t & 63, wid = t >> 6;
    int wr = wid >> 2, wc = wid & 3;     // 2x4 waves, wave tile 64x64
    int nkt = nkt0;
    if (MODE == MODE_OUT) nkt = min(nkt, (brow + 128) / 32);

    // staging: linear LDS dest + inverse-swizzled source; swizzle byte^=(row&3)<<4
    int oA, oB0, oB1;
    const ushort* aS;
    const ushort* bS0;
    const ushort* bS1;
    {
        int o = t * 16;                       // A: 8 KB, 1 gload/thread
        int row = o >> 6;
        int colb = (o & 63) ^ ((row & 3) << 4);
        oA = o >> 1;
        aS = Ab + (size_t)(brow + row) * lda + (colb >> 1);
    }
    {
        int o = t * 16;                       // B gload 0
        int row = o >> 6;
        int colb = (o & 63) ^ ((row & 3) << 4);
        oB0 = o >> 1;
        bS0 = Bb + (size_t)(bcol + row) * ldb + (colb >> 1);
        o = (512 + t) * 16;                   // B gload 1
        row = o >> 6;
        colb = (o & 63) ^ ((row & 3) << 4);
        oB1 = o >> 1;
        bS1 = Bb + (size_t)(bcol + row) * ldb + (colb >> 1);
    }
    auto stage = [&](int tk, int slot) {      // 3 gloads
        GLOAD(&As[slot][0] + oA, aS + tk * 32);
        GLOAD(&Bs[slot][0] + oB0, bS0 + tk * 32);
        GLOAD(&Bs[slot][0] + oB1, bS1 + tk * 32);
    };

    // fragment read byte-offsets
    int rdA[4], rdB[4];
    #pragma unroll
    for (int m = 0; m < 4; ++m) {
        int ra = wr * 64 + m * 16 + (lane & 15);
        int cb = (lane >> 4) * 16;
        rdA[m] = ra * 64 + (cb ^ ((ra & 3) << 4));
    }
    #pragma unroll
    for (int n = 0; n < 4; ++n) {
        int rb = wc * 64 + n * 16 + (lane & 15);
        int cb = (lane >> 4) * 16;
        rdB[n] = rb * 64 + (cb ^ ((rb & 3) << 4));
    }

    f32x4_t acc[4][4];
    #pragma unroll
    for (int m = 0; m < 4; ++m)
        #pragma unroll
        for (int n = 0; n < 4; ++n)
            acc[m][n] = (f32x4_t){0.f, 0.f, 0.f, 0.f};

    // prologue: stage tiles 0,1; gate tile0 only (tile1 stays in flight)
    stage(0, 0);
    stage(1, 1);
    GATE(3);
    __builtin_amdgcn_s_barrier();

    for (int kt = 0; kt < nkt; ++kt) {
        int cur = kt % 3;
        int s2 = kt + 2 < nkt ? (kt + 2) % 3 : 0;
        if (kt + 2 < nkt) stage(kt + 2, s2);   // overwrites slot read at kt-1 (safe: barrier)

        const char* bA = (const char*)&As[cur][0];
        const char* bB = (const char*)&Bs[cur][0];
        bf16x8_t af[4], bf[4];
        #pragma unroll
        for (int m = 0; m < 4; ++m) af[m] = *(const bf16x8_t*)(bA + rdA[m]);
        #pragma unroll
        for (int n = 0; n < 4; ++n) bf[n] = *(const bf16x8_t*)(bB + rdB[n]);

        __builtin_amdgcn_s_setprio(1);
        #pragma unroll
        for (int m = 0; m < 4; ++m)
            #pragma unroll
            for (int n = 0; n < 4; ++n)
                acc[m][n] = __builtin_amdgcn_mfma_f32_16x16x32_bf16(
                    af[m], bf[n], acc[m][n], 0, 0, 0);
        __builtin_amdgcn_s_setprio(0);

        if (kt + 1 < nkt) {
            if (kt + 2 < nkt) { GATE(3); }     // drain tile kt+1 (2 iterations in flight)
            else              { GATE(0); }
        }
        __builtin_amdgcn_s_barrier();
    }

    // epilogue: C/D layout col = lane&15, row = (lane>>4)*4 + j
    int crow0 = brow + wr * 64 + ((lane >> 4) * 4);
    int ccol0 = bcol + wc * 64 + (lane & 15);
    if (MODE == MODE_PROJ) {
        #pragma unroll
        for (int mf = 0; mf < 4; ++mf) {
            #pragma unroll
            for (int nf = 0; nf < 4; ++nf) {
                int gcol = ccol0 + nf * 16;
                float bv = bias[gcol];
                int rowg = crow0 + mf * 16;
                if (gcol < D_DIM) {            // qq bf16 [8192][1024]
                    ushort* C = (ushort*)Cout;
                    #pragma unroll
                    for (int j = 0; j < 4; ++j)
                        C[(size_t)(rowg + j) * D_DIM + gcol] = f32_to_bf16(acc[mf][nf][j] + bv);
                } else {                       // vpT [B][1024][2048]
                    int d = gcol - D_DIM;
                    int b = rowg >> 11, s = rowg & 2047;
                    ushort4 o;
                    o.x = f32_to_bf16(acc[mf][nf][0] + bv);
                    o.y = f32_to_bf16(acc[mf][nf][1] + bv);
                    o.z = f32_to_bf16(acc[mf][nf][2] + bv);
                    o.w = f32_to_bf16(acc[mf][nf][3] + bv);
                    *(ushort4*)&vpTp[((size_t)b * D_DIM + d) * S_LEN + s] = o;
                }
            }
        }
    } else if (MODE == MODE_MT) {
        ushort* C = (ushort*)Cout;
        #pragma unroll
        for (int mf = 0; mf < 4; ++mf)
            #pragma unroll
            for (int nf = 0; nf < 4; ++nf) {
                int gcol = ccol0 + nf * 16;
                int rowg = crow0 + mf * 16;
                #pragma unroll
                for (int j = 0; j < 4; ++j)
                    C[(size_t)(rowg + j) * ldc + gcol] = f32_to_bf16(acc[mf][nf][j]);
            }
    } else {
        float* C = (float*)Cout + (size_t)bz * strideC;
        #pragma unroll
        for (int mf = 0; mf < 4; ++mf)
            #pragma unroll
            for (int nf = 0; nf < 4; ++nf) {
                int gcol = ccol0 + nf * 16;
                int rowg = crow0 + mf * 16;
                #pragma unroll
                for (int j = 0; j < 4; ++j)
                    C[(size_t)(rowg + j) * ldc + gcol] = acc[mf][nf][j] * scale;
            }
    }
}

// ---------------- causal row softmax (+column term), skips masked chunks ----------------
__global__ __launch_bounds__(256)
void softmax_causal_kernel(float* __restrict__ attn, ushort* __restrict__ attn_bf,
                           const float* __restrict__ w) {
    int rowid = blockIdx.x;
    int i = rowid & (S_LEN - 1);
    float* lrow = attn + (size_t)rowid * S_LEN;
    ushort* brw = attn_bf + (size_t)rowid * S_LEN;
    const float* wv = w + (rowid & ~(S_LEN - 1));
    int t = threadIdx.x;
    int nvalid = i + 1;
    int nact = (nvalid + 255) >> 8;

    float vals[8];
    float lmax = -1e30f;
    #pragma unroll
    for (int it = 0; it < 8; ++it) {
        if (it < nact) {
            int j = it * 256 + t;
            float v = (j < nvalid) ? (lrow[j] + wv[j]) : -1e30f;
            vals[it] = v;
            lmax = fmaxf(lmax, v);
        }
    }
    #pragma unroll
    for (int off = 32; off > 0; off >>= 1)
        lmax = fmaxf(lmax, __shfl_xor(lmax, off));

    __shared__ float redm[4];
    __shared__ float reds[4];
    int wave = t >> 6, lane = t & 63;
    if (lane == 0) redm[wave] = lmax;
    __syncthreads();
    float m = fmaxf(fmaxf(redm[0], redm[1]), fmaxf(redm[2], redm[3]));

    float lsum = 0.f;
    #pragma unroll
    for (int it = 0; it < 8; ++it) {
        if (it < nact) {
            int j = it * 256 + t;
            float e = (j < nvalid) ? __expf(vals[it] - m) : 0.f;
            vals[it] = e;
            lsum += e;
        }
    }
    #pragma unroll
    for (int off = 32; off > 0; off >>= 1)
        lsum += __shfl_xor(lsum, off);
    if (lane == 0) reds[wave] = lsum;
    __syncthreads();
    float denom = reds[0] + reds[1] + reds[2] + reds[3];
    float inv = 1.f / denom;

    #pragma unroll
    for (int it = 0; it < 8; ++it) {
        int j = it * 256 + t;
        if (it < nact) {
            float p = vals[it] * inv;
            lrow[j] = p;
            brw[j] = f32_to_bf16(p);
        } else {
            lrow[j] = 0.f;     // fp32 attn output needs zeros everywhere
        }                      // bf16 beyond nact never read by PV (K-limit)
    }
}

extern "C" void kernel_launch(void* const* d_in, const int* in_sizes, int n_in,
                              void* d_out, int out_size, void* d_ws, size_t ws_size,
                              hipStream_t stream) {
    const float* v  = (const float*)d_in[0];
    const float* k  = (const float*)d_in[1];
    const float* q  = (const float*)d_in[2];
    // d_in[3] = mask, unused (causality applied by index)
    const float* Wq = (const float*)d_in[4];
    const float* bq = (const float*)d_in[5];
    const float* Wk = (const float*)d_in[6];
    const float* bk = (const float*)d_in[7];   // (bk enters only via u_i which cancels in softmax)
    const float* Wv = (const float*)d_in[8];
    const float* bv = (const float*)d_in[9];

    float* out  = (float*)d_out;                                        // [B,S,D]
    float* attn = (float*)d_out + (size_t)BATCH * S_LEN * D_DIM;        // [B,S,S]

    char* ws = (char*)d_ws;
    const size_t MB = 1024u * 1024u;
    const size_t NTOK = (size_t)BATCH * S_LEN;                 // 8192
    ushort* xqkv  = (ushort*)(ws);                             // [3][8192][1024] bf16 @0 (48MB)
    ushort* xq    = xqkv;
    ushort* xk    = xqkv + NTOK * D_DIM;
    ushort* qq    = (ushort*)(ws + 48 * MB);                   // [8192][1024] bf16 (16MB)
    ushort* vpT   = (ushort*)(ws + 64 * MB);                   // [B][1024][2048] bf16 (16MB)
    ushort* Btp   = (ushort*)(ws + 80 * MB);                   // [2048][1024] bf16 (4MB): MT | WvT
    ushort* xW    = (ushort*)(ws + 84 * MB);                   // [2][1024][1024] bf16 (4MB): xWk | xWq
    float*  bias2 = (float*)(ws + 88 * MB);                    // [2048]
    float*  zb    = (float*)(ws + 88 * MB + 8192);             // [2048]
    float*  hvb   = (float*)(ws + 88 * MB + 16384);            // [1024]
    float*  wvec  = (float*)(ws + 88 * MB + 20480);            // [8192]
    ushort* attn_bf = (ushort*)(ws);                           // [B][2048][2048] bf16 alias over xq|xk

    const int n4 = (int)(NTOK * D_DIM / 4);
    cvt3_kernel<<<dim3(1024, 3), dim3(256), 0, stream>>>(q, k, v, xqkv, n4);
    cvt2_kernel<<<dim3(256, 2), dim3(256), 0, stream>>>(Wk, Wq, xW, D_DIM * D_DIM / 4);
    transpose_cvt_kernel<<<dim3(16, 16), dim3(256), 0, stream>>>(Wv, Btp + (size_t)D_DIM * D_DIM, D_DIM, D_DIM);
    fill_kernel<<<dim3(8), dim3(256), 0, stream>>>(bv, bias2, zb);
    hv_kernel<<<dim3(256), dim3(256), 0, stream>>>(Wk, bq, hvb);
    wvec_kernel<<<dim3(2048), dim3(256), 0, stream>>>(xk, hvb, wvec);

    // MT[e,d] = sum_c Wk[e,c] * Wq[d,c]  -> Btp rows 0..1023
    gemm_t_kernel<MODE_MT><<<dim3(4, 8, 1), dim3(512), 0, stream>>>(
        xW, xW + (size_t)D_DIM * D_DIM, zb, Btp, nullptr,
        D_DIM / 32, D_DIM, D_DIM, D_DIM, 0, 0, 0, 1.f);

    // proj: qq = q.M (cols 0..1023), vp = v.Wv + bv -> vpT (cols 1024..2047)
    gemm_t_kernel<MODE_PROJ><<<dim3(8, 64, 1), dim3(512), 0, stream>>>(
        xqkv, Btp, bias2, qq, vpT,
        D_DIM / 32, D_DIM, D_DIM, D_DIM, (long)NTOK * D_DIM, 0, 0, 1.f);

    // logits = qq . k^T / 32 (causal blocks only) -> attn fp32
    gemm_t_kernel<MODE_LOGITS><<<dim3(8, 16, BATCH), dim3(512), 0, stream>>>(
        qq, xk, nullptr, attn, nullptr,
        D_DIM / 32, D_DIM, D_DIM, S_LEN,
        (long)S_LEN * D_DIM, (long)S_LEN * D_DIM, (long)S_LEN * S_LEN, 0.03125f);

    // softmax rows (adds column term w; fp32 attn + bf16 copy for PV)
    softmax_causal_kernel<<<dim3((int)NTOK), dim3(256), 0, stream>>>(attn, attn_bf, wvec);

    // out = attn_bf @ vp (via vpT), causal K-limit
    gemm_t_kernel<MODE_OUT><<<dim3(4, 16, BATCH), dim3(512), 0, stream>>>(
        attn_bf, vpT, nullptr, out, nullptr,
        S_LEN / 32, S_LEN, S_LEN, D_DIM,
        (long)S_LEN * S_LEN, (long)D_DIM * S_LEN, (long)S_LEN * D_DIM, 1.f);
}

// Round 9
// 219.554 us; speedup vs baseline: 1.0846x; 1.0846x over previous
//
#include <hip/hip_runtime.h>
#include <hip/hip_bf16.h>
#include <cstdint>

#define BATCH 4
#define S_LEN 2048
#define D_DIM 1024

typedef __attribute__((ext_vector_type(4))) float f32x4_t;
typedef __attribute__((ext_vector_type(8))) __bf16 bf16x8_t;

__device__ __forceinline__ ushort f32_to_bf16(float f) {
    uint32_t u = __float_as_uint(f);
    uint32_t r = (u + 0x7FFFu + ((u >> 16) & 1u)) >> 16;
    return (ushort)r;
}

// ---------------- fp32 -> bf16 convert, 5 tensors in one launch ----------------
// z=0..2: q,k,v (1024 n4-blocks each); z=3: Wk|Wq (512 n4-blocks)
__global__ __launch_bounds__(256)
void cvt_all_kernel(const float* __restrict__ q, const float* __restrict__ k,
                    const float* __restrict__ v, const float* __restrict__ wk,
                    const float* __restrict__ wq,
                    ushort* __restrict__ xqkv, ushort* __restrict__ xw, int n4) {
    int z = blockIdx.y;
    const float* src;
    ushort* dst;
    int n;
    if (z < 3) {
        src = (z == 0) ? q : ((z == 1) ? k : v);
        dst = xqkv + (size_t)z * n4 * 4;
        n = n4;
    } else {
        src = nullptr; dst = nullptr; n = 0;
    }
    int idx = blockIdx.x * blockDim.x + threadIdx.x;
    int stride = gridDim.x * blockDim.x;
    if (z < 3) {
        const float4* in4 = (const float4*)src;
        ushort4* out4 = (ushort4*)dst;
        for (int i = idx; i < n; i += stride) {
            float4 vv = in4[i];
            ushort4 o;
            o.x = f32_to_bf16(vv.x);
            o.y = f32_to_bf16(vv.y);
            o.z = f32_to_bf16(vv.z);
            o.w = f32_to_bf16(vv.w);
            out4[i] = o;
        }
    } else {
        int nw = D_DIM * D_DIM / 4;   // per weight matrix
        const float4* ik = (const float4*)wk;
        const float4* iq = (const float4*)wq;
        ushort4* ok = (ushort4*)xw;
        ushort4* oq = (ushort4*)(xw + (size_t)D_DIM * D_DIM);
        for (int i = idx; i < nw; i += stride) {
            float4 a = ik[i];
            ushort4 o;
            o.x = f32_to_bf16(a.x); o.y = f32_to_bf16(a.y);
            o.z = f32_to_bf16(a.z); o.w = f32_to_bf16(a.w);
            ok[i] = o;
            float4 b = iq[i];
            o.x = f32_to_bf16(b.x); o.y = f32_to_bf16(b.y);
            o.z = f32_to_bf16(b.z); o.w = f32_to_bf16(b.w);
            oq[i] = o;
        }
    }
}

// ---------------- fp32 [rows][cols] -> bf16 [cols][rows] (Wv) ----------------
__global__ __launch_bounds__(256)
void transpose_cvt_kernel(const float* __restrict__ in, ushort* __restrict__ out,
                          int rows, int cols) {
    __shared__ ushort tile[64][66];
    int r0 = blockIdx.y * 64, c0 = blockIdx.x * 64;
    int t = threadIdx.x;
    int cr = t & 63;
    int cc = t >> 6;
    #pragma unroll
    for (int i = 0; i < 16; ++i) {
        int r = cc * 16 + i;
        tile[r][cr] = f32_to_bf16(in[(size_t)(r0 + r) * cols + (c0 + cr)]);
    }
    __syncthreads();
    #pragma unroll
    for (int i = 0; i < 16; ++i) {
        int c = cc * 16 + i;
        out[(size_t)(c0 + c) * rows + (r0 + cr)] = tile[cr][c];
    }
}

// ---------------- bias2 = [0 | bv] ----------------
__global__ __launch_bounds__(256)
void fill_kernel(const float* __restrict__ bv, float* __restrict__ bias2) {
    int i = blockIdx.x * blockDim.x + threadIdx.x;   // 0..2047
    bias2[i] = (i < D_DIM) ? 0.f : bv[i - D_DIM];
}

// ---------------- hv[e] = Wk[e,:] . bq ----------------
__global__ __launch_bounds__(256)
void hv_kernel(const float* __restrict__ Wk, const float* __restrict__ bq,
               float* __restrict__ hv) {
    int wave = threadIdx.x >> 6, lane = threadIdx.x & 63;
    int r = blockIdx.x * 4 + wave;     // 1024 rows, grid 256
    const float* row = Wk + (size_t)r * D_DIM;
    float s = 0.f;
    #pragma unroll
    for (int it = 0; it < 16; ++it)
        s += row[it * 64 + lane] * bq[it * 64 + lane];
    #pragma unroll
    for (int off = 32; off > 0; off >>= 1)
        s += __shfl_xor(s, off);
    if (lane == 0) hv[r] = s;
}

// ---------------- w[r] = (xk[r,:] . hv) / 32 ----------------
__global__ __launch_bounds__(256)
void wvec_kernel(const ushort* __restrict__ xk, const float* __restrict__ hv,
                 float* __restrict__ w) {
    int wave = threadIdx.x >> 6, lane = threadIdx.x & 63;
    int r = blockIdx.x * 4 + wave;     // 8192 rows, grid 2048
    const ushort* row = xk + (size_t)r * D_DIM + lane * 16;
    const float* hp = hv + lane * 16;
    float s = 0.f;
    #pragma unroll
    for (int it = 0; it < 16; ++it) {
        uint32_t u = row[it];
        s += __uint_as_float(u << 16) * hp[it];
    }
    #pragma unroll
    for (int off = 32; off > 0; off >>= 1)
        s += __shfl_xor(s, off);
    if (lane == 0) w[r] = s * 0.03125f;
}

enum { MODE_PROJ = 0, MODE_MT = 1, MODE_LOGITS = 2 };

#define PRE_BAR() do { __builtin_amdgcn_s_barrier(); \
    asm volatile("s_waitcnt lgkmcnt(0)" ::: "memory"); \
    __builtin_amdgcn_sched_barrier(0); } while (0)
#define POST_BAR() do { __builtin_amdgcn_sched_barrier(0); \
    __builtin_amdgcn_s_barrier(); } while (0)
#define GATE(N) do { asm volatile("s_waitcnt vmcnt(" #N ")" ::: "memory"); \
    __builtin_amdgcn_sched_barrier(0); } while (0)

#define GLOAD(dst, src) __builtin_amdgcn_global_load_lds( \
    (const __attribute__((address_space(1))) uint32_t*)(src), \
    (__attribute__((address_space(3))) uint32_t*)(dst), 16, 0, 0)

// bijective XCD swizzle over (x,y) grid (requires nwg%8==0)
__device__ __forceinline__ void xcd_swizzle(int& bc, int& br) {
    int gx = gridDim.x;
    int nwg = gx * gridDim.y;
    int orig = blockIdx.y * gx + blockIdx.x;
    int xcd = orig & 7, idx = orig >> 3;
    int wgid = xcd * (nwg >> 3) + idx;
    bc = wgid % gx;
    br = wgid / gx;
}

// =====================================================================
// 256x256 GEMM, BK=64, 8 waves (2x4), wave tile 128x64, 2 LDS slots,
// 4 quadrant-phases per K-tile, counted vmcnt gates. C = A * Bt^T.
// =====================================================================
template<int MODE>
__global__ __launch_bounds__(512, 2)
void gemm_q_kernel(const ushort* __restrict__ A, const ushort* __restrict__ Bt,
                   const float* __restrict__ bias, void* __restrict__ Cout,
                   ushort* __restrict__ vpTp,
                   int K, int lda, int ldb, int ldc,
                   long strideA, long strideC, float scale) {
    __shared__ ushort As[2][256 * 64];   // 2 x 32 KB
    __shared__ ushort Bs[2][256 * 64];   // 2 x 32 KB
    int bc, br;
    xcd_swizzle(bc, br);
    int bz = blockIdx.z;
    if (MODE == MODE_LOGITS && bc > br) return;   // fully-masked causal block
    const ushort* Ab = (MODE == MODE_PROJ) ? A + (size_t)(bc >> 2) * strideA
                                           : A + (size_t)bz * strideA;
    const ushort* Bb = (MODE == MODE_LOGITS) ? Bt + (size_t)bz * strideA : Bt;
    int brow = br * 256, bcol = bc * 256;
    int t = threadIdx.x, lane = t & 63, wid = t >> 6;
    int wr = wid >> 2, wc = wid & 3;      // 2x4 waves; wave tile 128x64
    int nkt = K / 64;

    // staging: linear LDS dest + inverse-swizzled source; swizzle byte^=(row&7)<<4
    const ushort* aSrc[4];
    const ushort* bSrc[4];
    int oL[4];
    #pragma unroll
    for (int j = 0; j < 4; ++j) {
        int o = (j * 512 + t) * 16;
        int row = o >> 7;
        int colb = (o & 127) ^ ((row & 7) << 4);
        oL[j] = o >> 1;
        aSrc[j] = Ab + (size_t)(brow + row) * lda + (colb >> 1);
        bSrc[j] = Bb + (size_t)(bcol + row) * ldb + (colb >> 1);
    }
    auto stgA = [&](int tk, int slot, int j0, int j1) {
        ushort* d = &As[slot][0];
        GLOAD(d + oL[j0], aSrc[j0] + tk * 64);
        GLOAD(d + oL[j1], aSrc[j1] + tk * 64);
    };
    auto stgB = [&](int tk, int slot, int j0, int j1) {
        ushort* d = &Bs[slot][0];
        GLOAD(d + oL[j0], bSrc[j0] + tk * 64);
        GLOAD(d + oL[j1], bSrc[j1] + tk * 64);
    };

    // fragment read byte-offsets (ks=0; ks=1 is ^64)
    int rdA[2][4], rdB[4];
    #pragma unroll
    for (int mh = 0; mh < 2; ++mh)
        #pragma unroll
        for (int m = 0; m < 4; ++m) {
            int ra = wr * 128 + mh * 64 + m * 16 + (lane & 15);
            int cb = (lane >> 4) * 16;
            rdA[mh][m] = ra * 128 + (cb ^ ((ra & 7) << 4));
        }
    #pragma unroll
    for (int nf = 0; nf < 4; ++nf) {
        int rb = (nf >> 1) * 128 + wc * 32 + (nf & 1) * 16 + (lane & 15);
        int cb = (lane >> 4) * 16;
        rdB[nf] = rb * 128 + (cb ^ ((rb & 7) << 4));
    }

    f32x4_t acc[8][4];
    #pragma unroll
    for (int m = 0; m < 8; ++m)
        #pragma unroll
        for (int n = 0; n < 4; ++n)
            acc[m][n] = (f32x4_t){0.f, 0.f, 0.f, 0.f};

    bf16x8_t af[4][2], bfr[4][2];

    auto readAh = [&](int slot, int mh) {
        const char* base = (const char*)&As[slot][0];
        #pragma unroll
        for (int m = 0; m < 4; ++m) {
            af[m][0] = *(const bf16x8_t*)(base + rdA[mh][m]);
            af[m][1] = *(const bf16x8_t*)(base + (rdA[mh][m] ^ 64));
        }
    };
    auto readBh = [&](int slot, int nh) {
        const char* base = (const char*)&Bs[slot][0];
        #pragma unroll
        for (int n = 0; n < 2; ++n) {
            int nf = nh * 2 + n;
            bfr[nf][0] = *(const bf16x8_t*)(base + rdB[nf]);
            bfr[nf][1] = *(const bf16x8_t*)(base + (rdB[nf] ^ 64));
        }
    };

#define QUAD(MH, NH)                                                                \
    do { __builtin_amdgcn_s_setprio(1);                                             \
        _Pragma("unroll") for (int m = 0; m < 4; ++m)                               \
        _Pragma("unroll") for (int n = 0; n < 2; ++n)                               \
        _Pragma("unroll") for (int ks = 0; ks < 2; ++ks)                            \
            acc[(MH) * 4 + m][(NH) * 2 + n] = __builtin_amdgcn_mfma_f32_16x16x32_bf16( \
                af[m][ks], bfr[(NH) * 2 + n][ks], acc[(MH) * 4 + m][(NH) * 2 + n], 0, 0, 0); \
        __builtin_amdgcn_s_setprio(0); } while (0)

    // prologue: tile 0 fully, gate-friendly order: Bh0, Ah0, Bh1, Ah1
    stgB(0, 0, 0, 1); stgA(0, 0, 0, 2); stgB(0, 0, 2, 3); stgA(0, 0, 1, 3);
    GATE(4);
    __builtin_amdgcn_s_barrier();

    for (int y = 0; y < nkt; ++y) {
        int cur = y & 1, nxt = cur ^ 1;
        bool st = (y + 1 < nkt);
        // P1 (Q00): reads Ah0,Bh0(cur); stage Bh0'(y+1)
        readAh(cur, 0); readBh(cur, 0);
        if (st) stgB(y + 1, nxt, 0, 1);
        PRE_BAR(); QUAD(0, 0);
        if (st) { GATE(4); } else { GATE(2); }
        POST_BAR();
        // P2 (Q01): reads Bh1(cur); stage Ah0'(y+1)
        readBh(cur, 1);
        if (st) stgA(y + 1, nxt, 0, 2);
        PRE_BAR(); QUAD(0, 1);
        if (st) { GATE(4); } else { GATE(0); }
        POST_BAR();
        // P3 (Q11): reads Ah1(cur); stage Bh1'(y+1)
        readAh(cur, 1);
        if (st) stgB(y + 1, nxt, 2, 3);
        PRE_BAR(); QUAD(1, 1); POST_BAR();
        // P4 (Q10): no reads; stage Ah1'(y+1); gate next tile's P1 halves
        if (st) stgA(y + 1, nxt, 1, 3);
        PRE_BAR(); QUAD(1, 0);
        if (st) { GATE(4); }
        POST_BAR();
    }
#undef QUAD

    // epilogue: row = brow + wr*128 + mh*64 + m*16 + (lane>>4)*4 + j
    //           col = bcol + (nf>>1)*128 + wc*32 + (nf&1)*16 + (lane&15)
    int crow0 = brow + wr * 128 + ((lane >> 4) * 4);
    int ccol0 = wc * 32 + (lane & 15);
    if (MODE == MODE_PROJ) {
        #pragma unroll
        for (int mf = 0; mf < 8; ++mf) {
            int rowg = crow0 + (mf >> 2) * 64 + (mf & 3) * 16;
            #pragma unroll
            for (int nf = 0; nf < 4; ++nf) {
                int gcol = bcol + (nf >> 1) * 128 + ccol0 + (nf & 1) * 16;
                float bv = bias[gcol];
                if (gcol < D_DIM) {   // qq bf16 [8192][1024]
                    ushort* C = (ushort*)Cout;
                    #pragma unroll
                    for (int j = 0; j < 4; ++j)
                        C[(size_t)(rowg + j) * D_DIM + gcol] = f32_to_bf16(acc[mf][nf][j] + bv);
                } else {              // vpT [B][1024][2048]
                    int d = gcol - D_DIM;
                    int b = rowg >> 11, s = rowg & 2047;
                    ushort4 o;
                    o.x = f32_to_bf16(acc[mf][nf][0] + bv);
                    o.y = f32_to_bf16(acc[mf][nf][1] + bv);
                    o.z = f32_to_bf16(acc[mf][nf][2] + bv);
                    o.w = f32_to_bf16(acc[mf][nf][3] + bv);
                    *(ushort4*)&vpTp[((size_t)b * D_DIM + d) * S_LEN + s] = o;
                }
            }
        }
    } else if (MODE == MODE_MT) {
        ushort* C = (ushort*)Cout;
        #pragma unroll
        for (int mf = 0; mf < 8; ++mf) {
            int rowg = crow0 + (mf >> 2) * 64 + (mf & 3) * 16;
            #pragma unroll
            for (int nf = 0; nf < 4; ++nf) {
                int gcol = bcol + (nf >> 1) * 128 + ccol0 + (nf & 1) * 16;
                #pragma unroll
                for (int j = 0; j < 4; ++j)
                    C[(size_t)(rowg + j) * ldc + gcol] = f32_to_bf16(acc[mf][nf][j]);
            }
        }
    } else {
        float* C = (float*)Cout + (size_t)bz * strideC;
        #pragma unroll
        for (int mf = 0; mf < 8; ++mf) {
            int rowg = crow0 + (mf >> 2) * 64 + (mf & 3) * 16;
            #pragma unroll
            for (int nf = 0; nf < 4; ++nf) {
                int col = bcol + (nf >> 1) * 128 + ccol0 + (nf & 1) * 16;
                #pragma unroll
                for (int j = 0; j < 4; ++j)
                    C[(size_t)(rowg + j) * ldc + col] = acc[mf][nf][j] * scale;
            }
        }
    }
}

// =====================================================================
// OUT GEMM (r6/r7 pipelined): 256x128, BK=64, 3 slots, causal K-limit.
// =====================================================================
#define LGKM(N) do { asm volatile("s_waitcnt lgkmcnt(" #N ")" ::: "memory"); \
    __builtin_amdgcn_sched_barrier(0); } while (0)

__global__ __launch_bounds__(512, 2)
void gemm_out_kernel(const ushort* __restrict__ A, const ushort* __restrict__ Bt,
                     void* __restrict__ Cout,
                     int K, int lda, int ldb, int ldc,
                     long strideA, long strideB, long strideC, float scale) {
    __shared__ ushort As[3][256 * 64];
    __shared__ ushort Bs[3][128 * 64];
    int bc, br;
    xcd_swizzle(bc, br);
    int bz = blockIdx.z;
    const ushort* Ab = A + (size_t)bz * strideA;
    const ushort* Bb = Bt + (size_t)bz * strideB;
    int brow = br * 256, bcol = bc * 128;
    int t = threadIdx.x, lane = t & 63, wid = t >> 6;
    int wr = wid >> 1, wc = wid & 1;
    int nkt = min(K / 64, (brow + 256) / 64);

    const ushort* aSrc[4];
    const ushort* bSrc[2];
    int oA[4], oB[2];
    #pragma unroll
    for (int j = 0; j < 4; ++j) {
        int o = (j * 512 + t) * 16;
        int row = o >> 7;
        int col = (o & 127) ^ ((row & 7) << 4);
        oA[j] = o >> 1;
        aSrc[j] = Ab + (size_t)(brow + row) * lda + (col >> 1);
    }
    #pragma unroll
    for (int j = 0; j < 2; ++j) {
        int o = (j * 512 + t) * 16;
        int row = o >> 7;
        int col = (o & 127) ^ ((row & 7) << 4);
        oB[j] = o >> 1;
        bSrc[j] = Bb + (size_t)(bcol + row) * ldb + (col >> 1);
    }
    auto stage = [&](int tk, int slot) {
        ushort* dA = &As[slot][0];
        ushort* dB = &Bs[slot][0];
        #pragma unroll
        for (int j = 0; j < 4; ++j) GLOAD(dA + oA[j], aSrc[j] + tk * 64);
        #pragma unroll
        for (int j = 0; j < 2; ++j) GLOAD(dB + oB[j], bSrc[j] + tk * 64);
    };

    int rdA[4][2], rdB[4][2];
    #pragma unroll
    for (int m = 0; m < 4; ++m) {
        int ra = wr * 64 + m * 16 + (lane & 15);
        #pragma unroll
        for (int ks = 0; ks < 2; ++ks) {
            int cb = ks * 64 + ((lane >> 4) * 16);
            rdA[m][ks] = ra * 128 + (cb ^ ((ra & 7) << 4));
        }
    }
    #pragma unroll
    for (int n = 0; n < 4; ++n) {
        int rb = wc * 64 + n * 16 + (lane & 15);
        #pragma unroll
        for (int ks = 0; ks < 2; ++ks) {
            int cb = ks * 64 + ((lane >> 4) * 16);
            rdB[n][ks] = rb * 128 + (cb ^ ((rb & 7) << 4));
        }
    }

    f32x4_t acc[4][4];
    #pragma unroll
    for (int m = 0; m < 4; ++m)
        #pragma unroll
        for (int n = 0; n < 4; ++n)
            acc[m][n] = (f32x4_t){0.f, 0.f, 0.f, 0.f};

    bf16x8_t aE0[4], aE1[4], bE0[4], bE1[4];
    bf16x8_t aO0[4], aO1[4], bO0[4], bO1[4];

#define MF16(AV, BV)                                                           \
    do { __builtin_amdgcn_s_setprio(1);                                        \
        _Pragma("unroll") for (int m = 0; m < 4; ++m)                          \
        _Pragma("unroll") for (int n = 0; n < 4; ++n)                          \
            acc[m][n] = __builtin_amdgcn_mfma_f32_16x16x32_bf16(               \
                AV[m], BV[n], acc[m][n], 0, 0, 0);                             \
        __builtin_amdgcn_s_setprio(0); } while (0)

#define TILE_BODY(X, CA0, CA1, CB0, CB1, NA0, NA1, NB0, NB1)                   \
    do {                                                                       \
        int x_ = (X);                                                          \
        __builtin_amdgcn_s_barrier();                                          \
        if (x_ + 2 < nkt) stage(x_ + 2, (x_ + 2) % 3);                         \
        if (x_ + 1 < nkt) { if (x_ + 2 < nkt) { GATE(6); } else { GATE(0); } } \
        __builtin_amdgcn_s_barrier();                                          \
        {                                                                      \
            const char* nA = (const char*)&As[(x_ + 1) % 3][0];                \
            const char* nB = (const char*)&Bs[(x_ + 1) % 3][0];                \
            if (x_ + 1 < nkt) {                                                \
                _Pragma("unroll") for (int n = 0; n < 4; ++n)                  \
                    NB0[n] = *(const bf16x8_t*)(nB + rdB[n][0]);               \
                _Pragma("unroll") for (int m = 0; m < 4; ++m)                  \
                    NA0[m] = *(const bf16x8_t*)(nA + rdA[m][0]);               \
                LGKM(8);                                                       \
            } else { LGKM(0); }                                                \
            MF16(CA0, CB0);                                                    \
            if (x_ + 1 < nkt) {                                                \
                _Pragma("unroll") for (int n = 0; n < 4; ++n)                  \
                    NB1[n] = *(const bf16x8_t*)(nB + rdB[n][1]);               \
                _Pragma("unroll") for (int m = 0; m < 4; ++m)                  \
                    NA1[m] = *(const bf16x8_t*)(nA + rdA[m][1]);               \
            }                                                                  \
            MF16(CA1, CB1);                                                    \
        }                                                                      \
    } while (0)

    stage(0, 0);
    stage(1, 1);
    GATE(6);
    __builtin_amdgcn_s_barrier();
    {
        const char* pA = (const char*)&As[0][0];
        const char* pB = (const char*)&Bs[0][0];
        #pragma unroll
        for (int n = 0; n < 4; ++n) bE0[n] = *(const bf16x8_t*)(pB + rdB[n][0]);
        #pragma unroll
        for (int m = 0; m < 4; ++m) aE0[m] = *(const bf16x8_t*)(pA + rdA[m][0]);
        #pragma unroll
        for (int n = 0; n < 4; ++n) bE1[n] = *(const bf16x8_t*)(pB + rdB[n][1]);
        #pragma unroll
        for (int m = 0; m < 4; ++m) aE1[m] = *(const bf16x8_t*)(pA + rdA[m][1]);
    }

    int nhalf = nkt >> 1;
    for (int it = 0; it < nhalf; ++it) {
        int x = 2 * it;
        TILE_BODY(x,     aE0, aE1, bE0, bE1, aO0, aO1, bO0, bO1);
        TILE_BODY(x + 1, aO0, aO1, bO0, bO1, aE0, aE1, bE0, bE1);
    }
#undef TILE_BODY
#undef MF16

    float* C = (float*)Cout + (size_t)bz * strideC;
    int crow0 = brow + wr * 64 + ((lane >> 4) * 4);
    int ccol0 = bcol + wc * 64 + (lane & 15);
    #pragma unroll
    for (int mf = 0; mf < 4; ++mf)
        #pragma unroll
        for (int nf = 0; nf < 4; ++nf) {
            int col = ccol0 + nf * 16;
            #pragma unroll
            for (int j = 0; j < 4; ++j) {
                int rowg = crow0 + mf * 16 + j;
                C[(size_t)rowg * ldc + col] = acc[mf][nf][j] * scale;
            }
        }
}

// ---------------- causal row softmax (+column term), skips masked chunks ----------------
__global__ __launch_bounds__(256)
void softmax_causal_kernel(float* __restrict__ attn, ushort* __restrict__ attn_bf,
                           const float* __restrict__ w) {
    int rowid = blockIdx.x;
    int i = rowid & (S_LEN - 1);
    float* lrow = attn + (size_t)rowid * S_LEN;
    ushort* brw = attn_bf + (size_t)rowid * S_LEN;
    const float* wv = w + (rowid & ~(S_LEN - 1));
    int t = threadIdx.x;
    int nvalid = i + 1;
    int nact = (nvalid + 255) >> 8;

    float vals[8];
    float lmax = -1e30f;
    #pragma unroll
    for (int it = 0; it < 8; ++it) {
        if (it < nact) {
            int j = it * 256 + t;
            float v = (j < nvalid) ? (lrow[j] + wv[j]) : -1e30f;
            vals[it] = v;
            lmax = fmaxf(lmax, v);
        }
    }
    #pragma unroll
    for (int off = 32; off > 0; off >>= 1)
        lmax = fmaxf(lmax, __shfl_xor(lmax, off));

    __shared__ float redm[4];
    __shared__ float reds[4];
    int wave = t >> 6, lane = t & 63;
    if (lane == 0) redm[wave] = lmax;
    __syncthreads();
    float m = fmaxf(fmaxf(redm[0], redm[1]), fmaxf(redm[2], redm[3]));

    float lsum = 0.f;
    #pragma unroll
    for (int it = 0; it < 8; ++it) {
        if (it < nact) {
            int j = it * 256 + t;
            float e = (j < nvalid) ? __expf(vals[it] - m) : 0.f;
            vals[it] = e;
            lsum += e;
        }
    }
    #pragma unroll
    for (int off = 32; off > 0; off >>= 1)
        lsum += __shfl_xor(lsum, off);
    if (lane == 0) reds[wave] = lsum;
    __syncthreads();
    float denom = reds[0] + reds[1] + reds[2] + reds[3];
    float inv = 1.f / denom;

    #pragma unroll
    for (int it = 0; it < 8; ++it) {
        int j = it * 256 + t;
        if (it < nact) {
            float p = vals[it] * inv;
            lrow[j] = p;
            brw[j] = f32_to_bf16(p);
        } else {
            lrow[j] = 0.f;     // fp32 attn output needs zeros
        }                      // bf16 beyond nact*256 never read by PV K-limit
    }
}

extern "C" void kernel_launch(void* const* d_in, const int* in_sizes, int n_in,
                              void* d_out, int out_size, void* d_ws, size_t ws_size,
                              hipStream_t stream) {
    const float* v  = (const float*)d_in[0];
    const float* k  = (const float*)d_in[1];
    const float* q  = (const float*)d_in[2];
    // d_in[3] = mask, unused (causality applied by index)
    const float* Wq = (const float*)d_in[4];
    const float* bq = (const float*)d_in[5];
    const float* Wk = (const float*)d_in[6];
    // d_in[7] = bk: enters only via a per-row constant which cancels in softmax
    const float* Wv = (const float*)d_in[8];
    const float* bv = (const float*)d_in[9];

    float* out  = (float*)d_out;                                        // [B,S,D]
    float* attn = (float*)d_out + (size_t)BATCH * S_LEN * D_DIM;        // [B,S,S]

    char* ws = (char*)d_ws;
    const size_t MB = 1024u * 1024u;
    const size_t NTOK = (size_t)BATCH * S_LEN;                 // 8192
    ushort* xqkv  = (ushort*)(ws);                             // [3][8192][1024] bf16 (48MB)
    ushort* xq    = xqkv;
    ushort* xk    = xqkv + NTOK * D_DIM;
    ushort* qq    = (ushort*)(ws + 48 * MB);                   // [8192][1024] bf16 (16MB)
    ushort* vpT   = (ushort*)(ws + 64 * MB);                   // [B][1024][2048] bf16 (16MB)
    ushort* Bcat  = (ushort*)(ws + 80 * MB);                   // [2048][1024] bf16: M | WvT (4MB)
    ushort* xW    = (ushort*)(ws + 84 * MB);                   // [2][1024][1024] bf16: xWk|xWq (4MB)
    float*  bias2 = (float*)(ws + 88 * MB);                    // [2048]
    float*  hvb   = (float*)(ws + 88 * MB + 8192);             // [1024]
    float*  wvec  = (float*)(ws + 88 * MB + 16384);            // [8192]
    ushort* attn_bf = (ushort*)(ws);                           // [B][2048][2048] bf16 alias (xq|xk dead)

    const int n4 = (int)(NTOK * D_DIM / 4);
    cvt_all_kernel<<<dim3(1024, 4), dim3(256), 0, stream>>>(q, k, v, Wk, Wq, xqkv, xW, n4);
    transpose_cvt_kernel<<<dim3(16, 16), dim3(256), 0, stream>>>(Wv, Bcat + (size_t)D_DIM * D_DIM, D_DIM, D_DIM);
    fill_kernel<<<dim3(8), dim3(256), 0, stream>>>(bv, bias2);
    hv_kernel<<<dim3(256), dim3(256), 0, stream>>>(Wk, bq, hvb);
    wvec_kernel<<<dim3(2048), dim3(256), 0, stream>>>(xk, hvb, wvec);

    // M[e,d] = sum_c Wk[e,c] * Wq[d,c] -> Bcat rows 0..1023 (grid 16, nwg%8==0)
    gemm_q_kernel<MODE_MT><<<dim3(4, 4, 1), dim3(512), 0, stream>>>(
        xW, xW + (size_t)D_DIM * D_DIM, nullptr, Bcat, nullptr,
        D_DIM, D_DIM, D_DIM, D_DIM, 0, 0, 1.f);

    // proj: qq = q.M (cols<1024), vp = v.Wv + bv -> vpT (cols>=1024); grid 256 = 1 round
    gemm_q_kernel<MODE_PROJ><<<dim3(8, 32, 1), dim3(512), 0, stream>>>(
        xqkv, Bcat, bias2, qq, vpT,
        D_DIM, D_DIM, D_DIM, 2048, (long)2 * NTOK * D_DIM, 0, 1.f);

    // logits = qq . k^T / 32 (causal blocks only) -> attn fp32
    gemm_q_kernel<MODE_LOGITS><<<dim3(8, 8, BATCH), dim3(512), 0, stream>>>(
        qq, xk, nullptr, attn, nullptr,
        D_DIM, D_DIM, D_DIM, S_LEN,
        (long)S_LEN * D_DIM, (long)S_LEN * S_LEN, 0.03125f);

    // softmax rows (adds column term wvec; fp32 attn + bf16 copy for PV)
    softmax_causal_kernel<<<dim3((int)NTOK), dim3(256), 0, stream>>>(attn, attn_bf, wvec);

    // out = attn_bf @ vp (via vpT), causal K-limit
    gemm_out_kernel<<<dim3(8, 8, BATCH), dim3(512), 0, stream>>>(
        attn_bf, vpT, out, S_LEN, S_LEN, S_LEN, D_DIM,
        (long)S_LEN * S_LEN, (long)D_DIM * S_LEN, (long)S_LEN * D_DIM, 1.f);
}

// Round 10
// 207.234 us; speedup vs baseline: 1.1491x; 1.0595x over previous
//
#include <hip/hip_runtime.h>
#include <hip/hip_bf16.h>
#include <hip/hip_fp16.h>
#include <cstdint>

#define BATCH 4
#define S_LEN 2048
#define D_DIM 1024

typedef __attribute__((ext_vector_type(4))) float f32x4_t;
typedef __attribute__((ext_vector_type(8))) __bf16 bf16x8_t;

__device__ __forceinline__ ushort f32_to_bf16(float f) {
    uint32_t u = __float_as_uint(f);
    uint32_t r = (u + 0x7FFFu + ((u >> 16) & 1u)) >> 16;
    return (ushort)r;
}
__device__ __forceinline__ ushort f32_to_f16(float f) {
    __half h = __float2half(f);
    return *(ushort*)&h;
}
__device__ __forceinline__ float f16_to_f32(ushort u) {
    __half h = *(__half*)&u;
    return __half2float(h);
}

// ---------------- fp32 -> bf16 convert, q/k/v + Wk|Wq in one launch ----------------
__global__ __launch_bounds__(256)
void cvt_all_kernel(const float* __restrict__ q, const float* __restrict__ k,
                    const float* __restrict__ v, const float* __restrict__ wk,
                    const float* __restrict__ wq,
                    ushort* __restrict__ xqkv, ushort* __restrict__ xw, int n4) {
    int z = blockIdx.y;
    int idx = blockIdx.x * blockDim.x + threadIdx.x;
    int stride = gridDim.x * blockDim.x;
    if (z < 3) {
        const float* src = (z == 0) ? q : ((z == 1) ? k : v);
        ushort* dst = xqkv + (size_t)z * n4 * 4;
        const float4* in4 = (const float4*)src;
        ushort4* out4 = (ushort4*)dst;
        for (int i = idx; i < n4; i += stride) {
            float4 vv = in4[i];
            ushort4 o;
            o.x = f32_to_bf16(vv.x);
            o.y = f32_to_bf16(vv.y);
            o.z = f32_to_bf16(vv.z);
            o.w = f32_to_bf16(vv.w);
            out4[i] = o;
        }
    } else {
        int nw = D_DIM * D_DIM / 4;
        const float4* ik = (const float4*)wk;
        const float4* iq = (const float4*)wq;
        ushort4* ok = (ushort4*)xw;
        ushort4* oq = (ushort4*)(xw + (size_t)D_DIM * D_DIM);
        for (int i = idx; i < nw; i += stride) {
            float4 a = ik[i];
            ushort4 o;
            o.x = f32_to_bf16(a.x); o.y = f32_to_bf16(a.y);
            o.z = f32_to_bf16(a.z); o.w = f32_to_bf16(a.w);
            ok[i] = o;
            float4 b = iq[i];
            o.x = f32_to_bf16(b.x); o.y = f32_to_bf16(b.y);
            o.z = f32_to_bf16(b.z); o.w = f32_to_bf16(b.w);
            oq[i] = o;
        }
    }
}

// ---------------- fp32 [rows][cols] -> bf16 [cols][rows] (Wv) ----------------
__global__ __launch_bounds__(256)
void transpose_cvt_kernel(const float* __restrict__ in, ushort* __restrict__ out,
                          int rows, int cols) {
    __shared__ ushort tile[64][66];
    int r0 = blockIdx.y * 64, c0 = blockIdx.x * 64;
    int t = threadIdx.x;
    int cr = t & 63;
    int cc = t >> 6;
    #pragma unroll
    for (int i = 0; i < 16; ++i) {
        int r = cc * 16 + i;
        tile[r][cr] = f32_to_bf16(in[(size_t)(r0 + r) * cols + (c0 + cr)]);
    }
    __syncthreads();
    #pragma unroll
    for (int i = 0; i < 16; ++i) {
        int c = cc * 16 + i;
        out[(size_t)(c0 + c) * rows + (r0 + cr)] = tile[cr][c];
    }
}

// ---------------- bias2 = [0 | bv] ----------------
__global__ __launch_bounds__(256)
void fill_kernel(const float* __restrict__ bv, float* __restrict__ bias2) {
    int i = blockIdx.x * blockDim.x + threadIdx.x;
    bias2[i] = (i < D_DIM) ? 0.f : bv[i - D_DIM];
}

// ---------------- hv[e] = Wk[e,:] . bq ----------------
__global__ __launch_bounds__(256)
void hv_kernel(const float* __restrict__ Wk, const float* __restrict__ bq,
               float* __restrict__ hv) {
    int wave = threadIdx.x >> 6, lane = threadIdx.x & 63;
    int r = blockIdx.x * 4 + wave;
    const float* row = Wk + (size_t)r * D_DIM;
    float s = 0.f;
    #pragma unroll
    for (int it = 0; it < 16; ++it)
        s += row[it * 64 + lane] * bq[it * 64 + lane];
    #pragma unroll
    for (int off = 32; off > 0; off >>= 1)
        s += __shfl_xor(s, off);
    if (lane == 0) hv[r] = s;
}

// ---------------- w[r] = (xk[r,:] . hv) / 32 ----------------
__global__ __launch_bounds__(256)
void wvec_kernel(const ushort* __restrict__ xk, const float* __restrict__ hv,
                 float* __restrict__ w) {
    int wave = threadIdx.x >> 6, lane = threadIdx.x & 63;
    int r = blockIdx.x * 4 + wave;
    const ushort* row = xk + (size_t)r * D_DIM + lane * 16;
    const float* hp = hv + lane * 16;
    float s = 0.f;
    #pragma unroll
    for (int it = 0; it < 16; ++it) {
        uint32_t u = row[it];
        s += __uint_as_float(u << 16) * hp[it];
    }
    #pragma unroll
    for (int off = 32; off > 0; off >>= 1)
        s += __shfl_xor(s, off);
    if (lane == 0) w[r] = s * 0.03125f;
}

// ---------------- MT reduce: M = sum of 4 fp16 partials -> bf16 ----------------
__global__ __launch_bounds__(256)
void mt_reduce_kernel(const ushort* __restrict__ p, ushort* __restrict__ M) {
    int i = blockIdx.x * 1024 + threadIdx.x * 4;   // 1M elements, grid 1024
    const size_t N = (size_t)D_DIM * D_DIM;
    ushort4 a = *(const ushort4*)&p[i];
    ushort4 b = *(const ushort4*)&p[N + i];
    ushort4 c = *(const ushort4*)&p[2 * N + i];
    ushort4 d = *(const ushort4*)&p[3 * N + i];
    ushort4 o;
    o.x = f32_to_bf16(f16_to_f32(a.x) + f16_to_f32(b.x) + f16_to_f32(c.x) + f16_to_f32(d.x));
    o.y = f32_to_bf16(f16_to_f32(a.y) + f16_to_f32(b.y) + f16_to_f32(c.y) + f16_to_f32(d.y));
    o.z = f32_to_bf16(f16_to_f32(a.z) + f16_to_f32(b.z) + f16_to_f32(c.z) + f16_to_f32(d.z));
    o.w = f32_to_bf16(f16_to_f32(a.w) + f16_to_f32(b.w) + f16_to_f32(c.w) + f16_to_f32(d.w));
    *(ushort4*)&M[i] = o;
}

enum { MODE_PROJ = 0, MODE_MT = 1, MODE_LOGITS = 2 };

#define PRE_BAR() do { __builtin_amdgcn_s_barrier(); \
    asm volatile("s_waitcnt lgkmcnt(0)" ::: "memory"); \
    __builtin_amdgcn_sched_barrier(0); } while (0)
#define POST_BAR() do { __builtin_amdgcn_sched_barrier(0); \
    __builtin_amdgcn_s_barrier(); } while (0)
#define GATE(N) do { asm volatile("s_waitcnt vmcnt(" #N ")" ::: "memory"); \
    __builtin_amdgcn_sched_barrier(0); } while (0)

#define GLOAD(dst, src) __builtin_amdgcn_global_load_lds( \
    (const __attribute__((address_space(1))) uint32_t*)(src), \
    (__attribute__((address_space(3))) uint32_t*)(dst), 16, 0, 0)

// bijective XCD swizzle over (x,y) grid (requires nwg%8==0)
__device__ __forceinline__ void xcd_swizzle(int& bc, int& br) {
    int gx = gridDim.x;
    int nwg = gx * gridDim.y;
    int orig = blockIdx.y * gx + blockIdx.x;
    int xcd = orig & 7, idx = orig >> 3;
    int wgid = xcd * (nwg >> 3) + idx;
    bc = wgid % gx;
    br = wgid / gx;
}

// =====================================================================
// 256x256 GEMM, BK=64, 8 waves (2x4), wave tile 128x64, 2 LDS slots,
// 4 quadrant-phases per K-tile, counted vmcnt gates. C = A * Bt^T.
// MODE_PROJ: 2D grid; MODE_MT/MODE_LOGITS: 1D grid with split-K decode.
// =====================================================================
template<int MODE>
__global__ __launch_bounds__(512, 2)
void gemm_q_kernel(const ushort* __restrict__ A, const ushort* __restrict__ Bt,
                   const float* __restrict__ bias, void* __restrict__ Cout,
                   ushort* __restrict__ aux,
                   int K, int lda, int ldb, int ldc,
                   long strideA, long strideC, float scale) {
    __shared__ ushort As[2][256 * 64];   // 2 x 32 KB
    __shared__ ushort Bs[2][256 * 64];   // 2 x 32 KB

    int bc, br, bz = 0, kh = 0, tri = 0, koff = 0;
    if (MODE == MODE_PROJ) {
        xcd_swizzle(bc, br);
    } else {
        int nwg = gridDim.x;
        int orig = blockIdx.x;
        int widx = (orig & 7) * (nwg >> 3) + (orig >> 3);
        if (MODE == MODE_MT) {
            kh = widx & 3;
            int tile = widx >> 2;
            bc = tile & 3;
            br = tile >> 2;
            koff = kh << 8;       // kh * 256
        } else {
            kh = widx & 1;
            int rest = widx >> 1;           // 0..143
            bz = rest / 36;
            tri = rest - bz * 36;
            br = 0;
            while ((br + 1) * (br + 2) / 2 <= tri) ++br;
            bc = tri - br * (br + 1) / 2;
            koff = kh << 9;       // kh * 512
        }
    }

    const ushort* Ab = (MODE == MODE_PROJ) ? A + (size_t)(bc >> 2) * strideA
                                           : A + (size_t)bz * strideA;
    const ushort* Bb = (MODE == MODE_LOGITS) ? Bt + (size_t)bz * strideA : Bt;
    int brow = br * 256, bcol = bc * 256;
    int t = threadIdx.x, lane = t & 63, wid = t >> 6;
    int wr = wid >> 2, wc = wid & 3;      // 2x4 waves; wave tile 128x64
    int nkt = K / 64;

    // staging: linear LDS dest + inverse-swizzled source; swizzle byte^=(row&7)<<4
    const ushort* aSrc[4];
    const ushort* bSrc[4];
    int oL[4];
    #pragma unroll
    for (int j = 0; j < 4; ++j) {
        int o = (j * 512 + t) * 16;
        int row = o >> 7;
        int colb = (o & 127) ^ ((row & 7) << 4);
        oL[j] = o >> 1;
        aSrc[j] = Ab + (size_t)(brow + row) * lda + (colb >> 1) + koff;
        bSrc[j] = Bb + (size_t)(bcol + row) * ldb + (colb >> 1) + koff;
    }
    auto stgA = [&](int tk, int slot, int j0, int j1) {
        ushort* d = &As[slot][0];
        GLOAD(d + oL[j0], aSrc[j0] + tk * 64);
        GLOAD(d + oL[j1], aSrc[j1] + tk * 64);
    };
    auto stgB = [&](int tk, int slot, int j0, int j1) {
        ushort* d = &Bs[slot][0];
        GLOAD(d + oL[j0], bSrc[j0] + tk * 64);
        GLOAD(d + oL[j1], bSrc[j1] + tk * 64);
    };

    // fragment read byte-offsets (ks=0; ks=1 is ^64)
    int rdA[2][4], rdB[4];
    #pragma unroll
    for (int mh = 0; mh < 2; ++mh)
        #pragma unroll
        for (int m = 0; m < 4; ++m) {
            int ra = wr * 128 + mh * 64 + m * 16 + (lane & 15);
            int cb = (lane >> 4) * 16;
            rdA[mh][m] = ra * 128 + (cb ^ ((ra & 7) << 4));
        }
    #pragma unroll
    for (int nf = 0; nf < 4; ++nf) {
        int rb = (nf >> 1) * 128 + wc * 32 + (nf & 1) * 16 + (lane & 15);
        int cb = (lane >> 4) * 16;
        rdB[nf] = rb * 128 + (cb ^ ((rb & 7) << 4));
    }

    f32x4_t acc[8][4];
    #pragma unroll
    for (int m = 0; m < 8; ++m)
        #pragma unroll
        for (int n = 0; n < 4; ++n)
            acc[m][n] = (f32x4_t){0.f, 0.f, 0.f, 0.f};

    bf16x8_t af[4][2], bfr[4][2];

    auto readAh = [&](int slot, int mh) {
        const char* base = (const char*)&As[slot][0];
        #pragma unroll
        for (int m = 0; m < 4; ++m) {
            af[m][0] = *(const bf16x8_t*)(base + rdA[mh][m]);
            af[m][1] = *(const bf16x8_t*)(base + (rdA[mh][m] ^ 64));
        }
    };
    auto readBh = [&](int slot, int nh) {
        const char* base = (const char*)&Bs[slot][0];
        #pragma unroll
        for (int n = 0; n < 2; ++n) {
            int nf = nh * 2 + n;
            bfr[nf][0] = *(const bf16x8_t*)(base + rdB[nf]);
            bfr[nf][1] = *(const bf16x8_t*)(base + (rdB[nf] ^ 64));
        }
    };

#define QUAD(MH, NH)                                                                \
    do { __builtin_amdgcn_s_setprio(1);                                             \
        _Pragma("unroll") for (int m = 0; m < 4; ++m)                               \
        _Pragma("unroll") for (int n = 0; n < 2; ++n)                               \
        _Pragma("unroll") for (int ks = 0; ks < 2; ++ks)                            \
            acc[(MH) * 4 + m][(NH) * 2 + n] = __builtin_amdgcn_mfma_f32_16x16x32_bf16( \
                af[m][ks], bfr[(NH) * 2 + n][ks], acc[(MH) * 4 + m][(NH) * 2 + n], 0, 0, 0); \
        __builtin_amdgcn_s_setprio(0); } while (0)

    // prologue: tile 0 fully, gate-friendly order: Bh0, Ah0, Bh1, Ah1
    stgB(0, 0, 0, 1); stgA(0, 0, 0, 2); stgB(0, 0, 2, 3); stgA(0, 0, 1, 3);
    GATE(4);
    __builtin_amdgcn_s_barrier();

    for (int y = 0; y < nkt; ++y) {
        int cur = y & 1, nxt = cur ^ 1;
        bool st = (y + 1 < nkt);
        // P1 (Q00): reads Ah0,Bh0(cur); stage Bh0'(y+1)
        readAh(cur, 0); readBh(cur, 0);
        if (st) stgB(y + 1, nxt, 0, 1);
        PRE_BAR(); QUAD(0, 0);
        if (st) { GATE(4); } else { GATE(2); }
        POST_BAR();
        // P2 (Q01): reads Bh1(cur); stage Ah0'(y+1)
        readBh(cur, 1);
        if (st) stgA(y + 1, nxt, 0, 2);
        PRE_BAR(); QUAD(0, 1);
        if (st) { GATE(4); } else { GATE(0); }
        POST_BAR();
        // P3 (Q11): reads Ah1(cur); stage Bh1'(y+1)
        readAh(cur, 1);
        if (st) stgB(y + 1, nxt, 2, 3);
        PRE_BAR(); QUAD(1, 1); POST_BAR();
        // P4 (Q10): no reads; stage Ah1'(y+1); gate next tile's P1 halves
        if (st) stgA(y + 1, nxt, 1, 3);
        PRE_BAR(); QUAD(1, 0);
        if (st) { GATE(4); }
        POST_BAR();
    }
#undef QUAD

    // epilogue: local row = wr*128 + (mf>>2)*64 + (mf&3)*16 + (lane>>4)*4 + j
    //           local col = (nf>>1)*128 + wc*32 + (nf&1)*16 + (lane&15)
    int lrow0 = wr * 128 + ((lane >> 4) * 4);
    int lcol0 = wc * 32 + (lane & 15);
    if (MODE == MODE_PROJ) {
        #pragma unroll
        for (int mf = 0; mf < 8; ++mf) {
            int rowg = brow + lrow0 + (mf >> 2) * 64 + (mf & 3) * 16;
            #pragma unroll
            for (int nf = 0; nf < 4; ++nf) {
                int gcol = bcol + (nf >> 1) * 128 + lcol0 + (nf & 1) * 16;
                float bv = bias[gcol];
                if (gcol < D_DIM) {   // qq bf16 [8192][1024]
                    ushort* C = (ushort*)Cout;
                    #pragma unroll
                    for (int j = 0; j < 4; ++j)
                        C[(size_t)(rowg + j) * D_DIM + gcol] = f32_to_bf16(acc[mf][nf][j] + bv);
                } else {              // vpT [B][1024][2048]
                    int d = gcol - D_DIM;
                    int b = rowg >> 11, s = rowg & 2047;
                    ushort4 o;
                    o.x = f32_to_bf16(acc[mf][nf][0] + bv);
                    o.y = f32_to_bf16(acc[mf][nf][1] + bv);
                    o.z = f32_to_bf16(acc[mf][nf][2] + bv);
                    o.w = f32_to_bf16(acc[mf][nf][3] + bv);
                    *(ushort4*)&aux[((size_t)b * D_DIM + d) * S_LEN + s] = o;
                }
            }
        }
    } else if (MODE == MODE_MT) {
        // fp16 partial: aux + kh * D*D, [1024][1024]
        ushort* P = aux + (size_t)kh * D_DIM * D_DIM;
        #pragma unroll
        for (int mf = 0; mf < 8; ++mf) {
            int rowg = brow + lrow0 + (mf >> 2) * 64 + (mf & 3) * 16;
            #pragma unroll
            for (int nf = 0; nf < 4; ++nf) {
                int gcol = bcol + (nf >> 1) * 128 + lcol0 + (nf & 1) * 16;
                #pragma unroll
                for (int j = 0; j < 4; ++j)
                    P[(size_t)(rowg + j) * D_DIM + gcol] = f32_to_f16(acc[mf][nf][j]);
            }
        }
    } else {   // MODE_LOGITS
        if (kh == 0) {
            float* C = (float*)Cout + (size_t)bz * strideC;
            #pragma unroll
            for (int mf = 0; mf < 8; ++mf) {
                int rowg = brow + lrow0 + (mf >> 2) * 64 + (mf & 3) * 16;
                #pragma unroll
                for (int nf = 0; nf < 4; ++nf) {
                    int col = bcol + (nf >> 1) * 128 + lcol0 + (nf & 1) * 16;
                    #pragma unroll
                    for (int j = 0; j < 4; ++j)
                        C[(size_t)(rowg + j) * ldc + col] = acc[mf][nf][j] * scale;
                }
            }
        } else {
            // fp16 compact partial: aux + (bz*36 + tri) * 65536, [256][256]
            ushort* P = aux + ((size_t)(bz * 36 + tri) << 16);
            #pragma unroll
            for (int mf = 0; mf < 8; ++mf) {
                int lr = lrow0 + (mf >> 2) * 64 + (mf & 3) * 16;
                #pragma unroll
                for (int nf = 0; nf < 4; ++nf) {
                    int lc = (nf >> 1) * 128 + lcol0 + (nf & 1) * 16;
                    #pragma unroll
                    for (int j = 0; j < 4; ++j)
                        P[(size_t)(lr + j) * 256 + lc] = f32_to_f16(acc[mf][nf][j] * scale);
                }
            }
        }
    }
}

// =====================================================================
// OUT GEMM (pipelined): 256x128, BK=64, 3 slots, causal K-limit.
// =====================================================================
#define LGKM(N) do { asm volatile("s_waitcnt lgkmcnt(" #N ")" ::: "memory"); \
    __builtin_amdgcn_sched_barrier(0); } while (0)

__global__ __launch_bounds__(512, 2)
void gemm_out_kernel(const ushort* __restrict__ A, const ushort* __restrict__ Bt,
                     void* __restrict__ Cout,
                     int K, int lda, int ldb, int ldc,
                     long strideA, long strideB, long strideC, float scale) {
    __shared__ ushort As[3][256 * 64];
    __shared__ ushort Bs[3][128 * 64];
    int bc, br;
    xcd_swizzle(bc, br);
    int bz = blockIdx.z;
    const ushort* Ab = A + (size_t)bz * strideA;
    const ushort* Bb = Bt + (size_t)bz * strideB;
    int brow = br * 256, bcol = bc * 128;
    int t = threadIdx.x, lane = t & 63, wid = t >> 6;
    int wr = wid >> 1, wc = wid & 1;
    int nkt = min(K / 64, (brow + 256) / 64);

    const ushort* aSrc[4];
    const ushort* bSrc[2];
    int oA[4], oB[2];
    #pragma unroll
    for (int j = 0; j < 4; ++j) {
        int o = (j * 512 + t) * 16;
        int row = o >> 7;
        int col = (o & 127) ^ ((row & 7) << 4);
        oA[j] = o >> 1;
        aSrc[j] = Ab + (size_t)(brow + row) * lda + (col >> 1);
    }
    #pragma unroll
    for (int j = 0; j < 2; ++j) {
        int o = (j * 512 + t) * 16;
        int row = o >> 7;
        int col = (o & 127) ^ ((row & 7) << 4);
        oB[j] = o >> 1;
        bSrc[j] = Bb + (size_t)(bcol + row) * ldb + (col >> 1);
    }
    auto stage = [&](int tk, int slot) {
        ushort* dA = &As[slot][0];
        ushort* dB = &Bs[slot][0];
        #pragma unroll
        for (int j = 0; j < 4; ++j) GLOAD(dA + oA[j], aSrc[j] + tk * 64);
        #pragma unroll
        for (int j = 0; j < 2; ++j) GLOAD(dB + oB[j], bSrc[j] + tk * 64);
    };

    int rdA[4][2], rdB[4][2];
    #pragma unroll
    for (int m = 0; m < 4; ++m) {
        int ra = wr * 64 + m * 16 + (lane & 15);
        #pragma unroll
        for (int ks = 0; ks < 2; ++ks) {
            int cb = ks * 64 + ((lane >> 4) * 16);
            rdA[m][ks] = ra * 128 + (cb ^ ((ra & 7) << 4));
        }
    }
    #pragma unroll
    for (int n = 0; n < 4; ++n) {
        int rb = wc * 64 + n * 16 + (lane & 15);
        #pragma unroll
        for (int ks = 0; ks < 2; ++ks) {
            int cb = ks * 64 + ((lane >> 4) * 16);
            rdB[n][ks] = rb * 128 + (cb ^ ((rb & 7) << 4));
        }
    }

    f32x4_t acc[4][4];
    #pragma unroll
    for (int m = 0; m < 4; ++m)
        #pragma unroll
        for (int n = 0; n < 4; ++n)
            acc[m][n] = (f32x4_t){0.f, 0.f, 0.f, 0.f};

    bf16x8_t aE0[4], aE1[4], bE0[4], bE1[4];
    bf16x8_t aO0[4], aO1[4], bO0[4], bO1[4];

#define MF16(AV, BV)                                                           \
    do { __builtin_amdgcn_s_setprio(1);                                        \
        _Pragma("unroll") for (int m = 0; m < 4; ++m)                          \
        _Pragma("unroll") for (int n = 0; n < 4; ++n)                          \
            acc[m][n] = __builtin_amdgcn_mfma_f32_16x16x32_bf16(               \
                AV[m], BV[n], acc[m][n], 0, 0, 0);                             \
        __builtin_amdgcn_s_setprio(0); } while (0)

#define TILE_BODY(X, CA0, CA1, CB0, CB1, NA0, NA1, NB0, NB1)                   \
    do {                                                                       \
        int x_ = (X);                                                          \
        __builtin_amdgcn_s_barrier();                                          \
        if (x_ + 2 < nkt) stage(x_ + 2, (x_ + 2) % 3);                         \
        if (x_ + 1 < nkt) { if (x_ + 2 < nkt) { GATE(6); } else { GATE(0); } } \
        __builtin_amdgcn_s_barrier();                                          \
        {                                                                      \
            const char* nA = (const char*)&As[(x_ + 1) % 3][0];                \
            const char* nB = (const char*)&Bs[(x_ + 1) % 3][0];                \
            if (x_ + 1 < nkt) {                                                \
                _Pragma("unroll") for (int n = 0; n < 4; ++n)                  \
                    NB0[n] = *(const bf16x8_t*)(nB + rdB[n][0]);               \
                _Pragma("unroll") for (int m = 0; m < 4; ++m)                  \
                    NA0[m] = *(const bf16x8_t*)(nA + rdA[m][0]);               \
                LGKM(8);                                                       \
            } else { LGKM(0); }                                                \
            MF16(CA0, CB0);                                                    \
            if (x_ + 1 < nkt) {                                                \
                _Pragma("unroll") for (int n = 0; n < 4; ++n)                  \
                    NB1[n] = *(const bf16x8_t*)(nB + rdB[n][1]);               \
                _Pragma("unroll") for (int m = 0; m < 4; ++m)                  \
                    NA1[m] = *(const bf16x8_t*)(nA + rdA[m][1]);               \
            }                                                                  \
            MF16(CA1, CB1);                                                    \
        }                                                                      \
    } while (0)

    stage(0, 0);
    stage(1, 1);
    GATE(6);
    __builtin_amdgcn_s_barrier();
    {
        const char* pA = (const char*)&As[0][0];
        const char* pB = (const char*)&Bs[0][0];
        #pragma unroll
        for (int n = 0; n < 4; ++n) bE0[n] = *(const bf16x8_t*)(pB + rdB[n][0]);
        #pragma unroll
        for (int m = 0; m < 4; ++m) aE0[m] = *(const bf16x8_t*)(pA + rdA[m][0]);
        #pragma unroll
        for (int n = 0; n < 4; ++n) bE1[n] = *(const bf16x8_t*)(pB + rdB[n][1]);
        #pragma unroll
        for (int m = 0; m < 4; ++m) aE1[m] = *(const bf16x8_t*)(pA + rdA[m][1]);
    }

    int nhalf = nkt >> 1;
    for (int it = 0; it < nhalf; ++it) {
        int x = 2 * it;
        TILE_BODY(x,     aE0, aE1, bE0, bE1, aO0, aO1, bO0, bO1);
        TILE_BODY(x + 1, aO0, aO1, bO0, bO1, aE0, aE1, bE0, bE1);
    }
#undef TILE_BODY
#undef MF16

    float* C = (float*)Cout + (size_t)bz * strideC;
    int crow0 = brow + wr * 64 + ((lane >> 4) * 4);
    int ccol0 = bcol + wc * 64 + (lane & 15);
    #pragma unroll
    for (int mf = 0; mf < 4; ++mf)
        #pragma unroll
        for (int nf = 0; nf < 4; ++nf) {
            int col = ccol0 + nf * 16;
            #pragma unroll
            for (int j = 0; j < 4; ++j) {
                int rowg = crow0 + mf * 16 + j;
                C[(size_t)rowg * ldc + col] = acc[mf][nf][j] * scale;
            }
        }
}

// ---------------- causal row softmax (sums split-K partials + column term) ----------------
__global__ __launch_bounds__(256)
void softmax_causal_kernel(float* __restrict__ attn, ushort* __restrict__ attn_bf,
                           const float* __restrict__ w, const ushort* __restrict__ lgp) {
    int rowid = blockIdx.x;
    int bz = rowid >> 11;
    int i = rowid & (S_LEN - 1);
    int br = i >> 8;
    float* lrow = attn + (size_t)rowid * S_LEN;
    ushort* brw = attn_bf + (size_t)rowid * S_LEN;
    const float* wv = w + (rowid & ~(S_LEN - 1));
    int t = threadIdx.x;
    int nvalid = i + 1;
    int nact = br + 1;   // active 256-wide chunks

    float vals[8];
    float lmax = -1e30f;
    #pragma unroll
    for (int it = 0; it < 8; ++it) {
        if (it < nact) {
            int j = it * 256 + t;
            int tri = br * (br + 1) / 2 + it;
            float lp = f16_to_f32(lgp[((size_t)(bz * 36 + tri) << 16) + ((i & 255) << 8) + t]);
            float v = (j < nvalid) ? (lrow[j] + lp + wv[j]) : -1e30f;
            vals[it] = v;
            lmax = fmaxf(lmax, v);
        }
    }
    #pragma unroll
    for (int off = 32; off > 0; off >>= 1)
        lmax = fmaxf(lmax, __shfl_xor(lmax, off));

    __shared__ float redm[4];
    __shared__ float reds[4];
    int wave = t >> 6, lane = t & 63;
    if (lane == 0) redm[wave] = lmax;
    __syncthreads();
    float m = fmaxf(fmaxf(redm[0], redm[1]), fmaxf(redm[2], redm[3]));

    float lsum = 0.f;
    #pragma unroll
    for (int it = 0; it < 8; ++it) {
        if (it < nact) {
            int j = it * 256 + t;
            float e = (j < nvalid) ? __expf(vals[it] - m) : 0.f;
            vals[it] = e;
            lsum += e;
        }
    }
    #pragma unroll
    for (int off = 32; off > 0; off >>= 1)
        lsum += __shfl_xor(lsum, off);
    if (lane == 0) reds[wave] = lsum;
    __syncthreads();
    float denom = reds[0] + reds[1] + reds[2] + reds[3];
    float inv = 1.f / denom;

    #pragma unroll
    for (int it = 0; it < 8; ++it) {
        int j = it * 256 + t;
        if (it < nact) {
            float p = vals[it] * inv;
            lrow[j] = p;
            brw[j] = f32_to_bf16(p);
        } else {
            lrow[j] = 0.f;     // fp32 attn output needs zeros
        }                      // bf16 beyond nact*256 never read by PV K-limit
    }
}

extern "C" void kernel_launch(void* const* d_in, const int* in_sizes, int n_in,
                              void* d_out, int out_size, void* d_ws, size_t ws_size,
                              hipStream_t stream) {
    const float* v  = (const float*)d_in[0];
    const float* k  = (const float*)d_in[1];
    const float* q  = (const float*)d_in[2];
    // d_in[3] = mask, unused (causality applied by index)
    const float* Wq = (const float*)d_in[4];
    const float* bq = (const float*)d_in[5];
    const float* Wk = (const float*)d_in[6];
    // d_in[7] = bk: enters only via a per-row constant which cancels in softmax
    const float* Wv = (const float*)d_in[8];
    const float* bv = (const float*)d_in[9];

    float* out  = (float*)d_out;                                        // [B,S,D]
    float* attn = (float*)d_out + (size_t)BATCH * S_LEN * D_DIM;        // [B,S,S]

    char* ws = (char*)d_ws;
    const size_t MB = 1024u * 1024u;
    const size_t NTOK = (size_t)BATCH * S_LEN;                 // 8192
    // layout (dead-region reuse keeps peak <= 102 MB proven):
    ushort* xqkv  = (ushort*)(ws);                             // [3][8192][1024] bf16 [0,48)
    ushort* xk    = xqkv + NTOK * D_DIM;
    ushort* qq    = (ushort*)(ws + 48 * MB);                   // [8192][1024] bf16 [48,64)
    ushort* vpT   = (ushort*)(ws + 64 * MB);                   // [B][1024][2048] bf16 [64,80)
    ushort* Bcat  = (ushort*)(ws + 80 * MB);                   // [2048][1024] bf16: M|WvT [80,84) (dead post-proj)
    ushort* xW    = (ushort*)(ws + 84 * MB);                   // [2][1024][1024] bf16 [84,88) (dead post-MT)
    ushort* mtp   = (ushort*)(ws + 88 * MB);                   // [4][1024][1024] fp16 [88,96) (dead post-reduce)
    ushort* lgp   = (ushort*)(ws + 80 * MB);                   // [4*36][256][256] fp16 [80,98.9) (logits->softmax)
    float*  bias2 = (float*)(ws + 99 * MB);                    // [2048]
    float*  hvb   = (float*)(ws + 99 * MB + 8192);             // [1024]
    float*  wvec  = (float*)(ws + 99 * MB + 16384);            // [8192]
    ushort* attn_bf = (ushort*)(ws);                           // [B][2048][2048] bf16 alias (xq|xk dead)

    const int n4 = (int)(NTOK * D_DIM / 4);
    cvt_all_kernel<<<dim3(1024, 4), dim3(256), 0, stream>>>(q, k, v, Wk, Wq, xqkv, xW, n4);
    transpose_cvt_kernel<<<dim3(16, 16), dim3(256), 0, stream>>>(Wv, Bcat + (size_t)D_DIM * D_DIM, D_DIM, D_DIM);
    fill_kernel<<<dim3(8), dim3(256), 0, stream>>>(bv, bias2);
    hv_kernel<<<dim3(256), dim3(256), 0, stream>>>(Wk, bq, hvb);
    wvec_kernel<<<dim3(2048), dim3(256), 0, stream>>>(xk, hvb, wvec);

    // M partials: split-K x4, grid 64 blocks 1D; then reduce -> Bcat rows 0..1023
    gemm_q_kernel<MODE_MT><<<dim3(64), dim3(512), 0, stream>>>(
        xW, xW + (size_t)D_DIM * D_DIM, nullptr, nullptr, mtp,
        256, D_DIM, D_DIM, D_DIM, 0, 0, 1.f);
    mt_reduce_kernel<<<dim3(1024), dim3(256), 0, stream>>>(mtp, Bcat);

    // proj: qq = q.M (cols<1024), vp = v.Wv + bv -> vpT (cols>=1024); grid 256 = 1 round
    gemm_q_kernel<MODE_PROJ><<<dim3(8, 32, 1), dim3(512), 0, stream>>>(
        xqkv, Bcat, bias2, qq, vpT,
        D_DIM, D_DIM, D_DIM, 2048, (long)2 * NTOK * D_DIM, 0, 1.f);

    // logits split-K x2: 288 blocks (36 tri x 4 bz x 2 kh); kh0 -> fp32 attn, kh1 -> fp16 lgp
    gemm_q_kernel<MODE_LOGITS><<<dim3(288), dim3(512), 0, stream>>>(
        qq, xk, nullptr, attn, lgp,
        512, D_DIM, D_DIM, S_LEN,
        (long)S_LEN * D_DIM, (long)S_LEN * S_LEN, 0.03125f);

    // softmax rows (sums partials + column term wvec; fp32 attn + bf16 copy for PV)
    softmax_causal_kernel<<<dim3((int)NTOK), dim3(256), 0, stream>>>(attn, attn_bf, wvec, lgp);

    // out = attn_bf @ vp (via vpT), causal K-limit
    gemm_out_kernel<<<dim3(8, 8, BATCH), dim3(512), 0, stream>>>(
        attn_bf, vpT, out, S_LEN, S_LEN, S_LEN, D_DIM,
        (long)S_LEN * S_LEN, (long)D_DIM * S_LEN, (long)S_LEN * D_DIM, 1.f);
}